// Round 6
// baseline (329.289 us; speedup 1.0000x reference)
//
#include <hip/hip_runtime.h>

// CRF loss (B=1024, T=512, L=62, K=64) for MI355X / gfx950.
// One 64-lane wave per batch (lane j = state j), 1024 blocks -> 1 wave/SIMD:
// runtime = straggler chain length x per-step DEPENDENT LATENCY (no TLP).
//
// R6: FORWARD/BACKWARD SPLIT. R2(LDS) and R4(DPP) both sat at ~540 cy/step
// with VALUBusy <=29% -> per-step latency is structural. CRF logZ factorizes
// at any cut tm: logZ = log sum_i qf_tm[i] * qb_tm[i]. Run the forward chain
// (rows 1..tm) and backward chain (rows slen+1 .. tm+1) INTERLEAVED in one
// wave: two independent serial chains -> each fills the other's stall
// cycles, and sequential depth halves (512 -> ~256 pair-steps).
//   fwd: qf_j <- Wf_j * sum_i qf_i E[i][j]     (dot vs E columns)
//   bwd: qb_i <- sum_j E[i][j] * (Wb_j qb_j)   (dot vs E rows; Wb=0 on 62/63)
// bwd init is analytic: exp(row slen+1 obs) = delta(lane63) -> qb = E[:,63].
// Both chains: gather-all DPP/permlane tree (R4-validated probe network,
// both swap outputs kept -> each lane holds all 64 values, 32 h2 regs),
// 32 fdot2 on 8 accumulators, SAME-STEP exponent renorm (exact 2^-(ex+6),
// validated; R5's delayed renorm was an undamped resonator -> NaN collapse).
// E rows 62/63 are exactly 0 (trans=-10000), killing junk lanes in fwd;
// Wb=0 kills them in bwd. Combine: S = sum_i hf_i*hb_i (hb=0 on 62/63),
// logZ2 = c_base + Ci_f + Ci_b + log2(S). Gold path fused; one atomicAdd.

#define SMALLF   (-1000.0f)
#define LOG2E_F  1.4426950408889634f
#define LN2_F    0.6931471805599453f

#if defined(__has_builtin)
#if __has_builtin(__builtin_amdgcn_exp2f)
#define EXP2F(x) __builtin_amdgcn_exp2f(x)
#else
#define EXP2F(x) exp2f(x)
#endif
#if __has_builtin(__builtin_amdgcn_logf)
#define LOG2F(x) __builtin_amdgcn_logf(x)
#else
#define LOG2F(x) log2f(x)
#endif
#else
#define EXP2F(x) exp2f(x)
#define LOG2F(x) log2f(x)
#endif

typedef _Float16 h2 __attribute__((ext_vector_type(2)));

#if defined(__has_builtin) && __has_builtin(__builtin_amdgcn_fdot2)
#define FDOT2(a, b, c) __builtin_amdgcn_fdot2((a), (b), (c), false)
#else
#define FDOT2(a, b, c) fmaf((float)(a).x, (float)(b).x, \
                            fmaf((float)(a).y, (float)(b).y, (c)))
#endif

// DPP move: dst[lane] = src[perm(lane)], full masks, all lanes active.
template <int CTRL>
__device__ __forceinline__ unsigned dppmov(unsigned v) {
    return (unsigned)__builtin_amdgcn_update_dpp((int)v, (int)v, CTRL, 0xF, 0xF, false);
}
#define DPP_QP_X1 0xB1   // quad_perm xor1
#define DPP_QP_X2 0x4E   // quad_perm xor2
#define DPP_ROR4  0x124
#define DPP_ROR8  0x128  // within-16 rotate 8 = xor8 either direction
#define DPP_ROR12 0x12C

// +-4 stage in the 16-row: ror4/ror12 select by lane bit2 -> net xor4 or
// xor12 (direction-dependent); either is an involution covering the other
// two quads; the probe records the exact row order.
__device__ __forceinline__ unsigned x4sel(unsigned v, bool b2) {
    const unsigned a = dppmov<DPP_ROR4>(v);
    const unsigned b = dppmov<DPP_ROR12>(v);
    return b2 ? a : b;
}

// Half-swap exchanges, BOTH outputs kept. Both operands are asm outputs that
// stay live afterward -> regalloc must keep them distinct. Together the two
// outputs cover both 16-(32-)lane groups; probe tracks the orientation.
#define SWAP16(a, b) asm("v_permlane16_swap_b32 %0, %1" : "+v"(a), "+v"(b))
#define SWAP32(a, b) asm("v_permlane32_swap_b32 %0, %1" : "+v"(a), "+v"(b))

__device__ __forceinline__ float bcast_first(float v) {
    return __uint_as_float(__builtin_amdgcn_readfirstlane(__float_as_uint(v)));
}

// SAME-STEP wave-uniform scale 2^-(ex+6) from ss_lane0; accumulates into Ci.
// (Validated in the 261.8us kernel and R4 — stable: lane0 pinned each step.)
__device__ __forceinline__ float step_scale(float ss, int& Ci) {
    const float s0 = bcast_first(ss);
    const int ex = (int)((__float_as_uint(s0) >> 23) & 0xFF) - 127;  // s0>0 normal
    Ci += ex + 6;
    return __uint_as_float((unsigned)(127 - ex - 6) << 23);          // exact 2^-(ex+6)
}

// ss[lane] = sum over ALL 64 slots i of h_i * Eh[i-in-probed-order][lane].
// Gather-all tree: pack(me,x1) -> x2 -> x4sel -> x8 -> swap16(both) ->
// swap32(both) = 32 h2 regs; 32 fdot2 on 8 accumulators; 3-level add tree.
__device__ __forceinline__ float step_ss(float hf,
                                         const h2* __restrict__ Eh,
                                         bool b2) {
    unsigned r[32];
    const unsigned n1 = dppmov<DPP_QP_X1>(__float_as_uint(hf));
    r[0] = __builtin_bit_cast(unsigned,
              __builtin_amdgcn_cvt_pkrtz(hf, __uint_as_float(n1)));
    r[1] = dppmov<DPP_QP_X2>(r[0]);
    r[2] = x4sel(r[0], b2);
    r[3] = x4sel(r[1], b2);
    r[4] = dppmov<DPP_ROR8>(r[0]);
    r[5] = dppmov<DPP_ROR8>(r[1]);
    r[6] = dppmov<DPP_ROR8>(r[2]);
    r[7] = dppmov<DPP_ROR8>(r[3]);
#pragma unroll
    for (int k = 0; k < 8; ++k) { r[8 + k] = r[k]; SWAP16(r[k], r[8 + k]); }
#pragma unroll
    for (int k = 0; k < 16; ++k) { r[16 + k] = r[k]; SWAP32(r[k], r[16 + k]); }
    float a[8];
#pragma unroll
    for (int j = 0; j < 8; ++j) a[j] = 0.f;
#pragma unroll
    for (int k = 0; k < 32; ++k)
        a[k & 7] = FDOT2(__builtin_bit_cast(h2, r[k]), Eh[k], a[k & 7]);
    return ((a[0] + a[1]) + (a[2] + a[3])) + ((a[4] + a[5]) + (a[6] + a[7]));
}

__global__ __launch_bounds__(64, 1) void crf_fused_kernel(
    const float* __restrict__ pred,     // (B,T,L)
    const int*   __restrict__ ref,      // (B,T)
    const int*   __restrict__ seq_len,  // (B,)
    const float* __restrict__ trans,    // (64,64)
    float*       __restrict__ out,      // scalar, pre-zeroed
    int T, int L)
{
    const int b    = blockIdx.x;
    const unsigned lane = threadIdx.x;
    const int slen = seq_len[b];
    const int nmid = slen - 1;              // middle steps (rows 2..slen)
    const float* prow = pred + (size_t)b * T * L;
    const int*   rrow = ref  + (size_t)b * T;
    const bool mine = (lane < 62);
    const bool b2 = (lane & 4u) != 0;

    // ---- gold score, two-phase gather (indices first, then values)
    int cidx[8], pidx[8];
#pragma unroll
    for (int k = 0; k < 8; ++k) {
        const int t = (int)lane + (k << 6);
        cidx[k] = (t < slen) ? rrow[t] : 0;
        pidx[k] = (t >= 1 && t < slen) ? rrow[t - 1] : 0;
    }
    float gacc = 0.f;
#pragma unroll
    for (int k = 0; k < 8; ++k) {
        const int t = (int)lane + (k << 6);
        if (t < slen) {
            gacc += prow[(size_t)t * L + cidx[k]];
            if (t >= 1) gacc += trans[(pidx[k] << 6) + cidx[k]];
        }
    }
    if (lane == 0)
        gacc += trans[(62 << 6) + rrow[0]] + trans[(rrow[slen - 1] << 6) + 63];

    // ---- probe the gather tree (payload = packed lane ids) ---------------
    unsigned gp[32];
    gp[0] = lane | (dppmov<DPP_QP_X1>(lane) << 16);
    gp[1] = dppmov<DPP_QP_X2>(gp[0]);
    gp[2] = x4sel(gp[0], b2);
    gp[3] = x4sel(gp[1], b2);
    gp[4] = dppmov<DPP_ROR8>(gp[0]);
    gp[5] = dppmov<DPP_ROR8>(gp[1]);
    gp[6] = dppmov<DPP_ROR8>(gp[2]);
    gp[7] = dppmov<DPP_ROR8>(gp[3]);
#pragma unroll
    for (int k = 0; k < 8; ++k) { gp[8 + k] = gp[k]; SWAP16(gp[k], gp[8 + k]); }
#pragma unroll
    for (int k = 0; k < 16; ++k) { gp[16 + k] = gp[k]; SWAP32(gp[k], gp[16 + k]); }

    // ---- E fragments in probed order ------------------------------------
    // Eh_f[k] = {E[rlo][lane], E[rhi][lane]}  (fwd: dot vs column `lane`)
    // Eh_b[k] = {E[lane][rlo], E[lane][rhi]}  (bwd: dot vs row `lane`)
    h2 Eh_f[32], Eh_b[32];
    float psum = 0.f;
#pragma unroll
    for (int k = 0; k < 32; ++k) {
        const unsigned rlo = gp[k] & 0xFFFFu;
        const unsigned rhi = gp[k] >> 16;
        const float f0 = EXP2F(trans[rlo * 64u + lane] * LOG2E_F);
        const float f1 = EXP2F(trans[rhi * 64u + lane] * LOG2E_F);
        Eh_f[k].x = (_Float16)f0; Eh_f[k].y = (_Float16)f1;
        psum += f0 + f1;                  // rows 62/63 contribute exactly 0
        const float g0 = EXP2F(trans[lane * 64u + rlo] * LOG2E_F);
        const float g1 = EXP2F(trans[lane * 64u + rhi] * LOG2E_F);
        Eh_b[k].x = (_Float16)g0; Eh_b[k].y = (_Float16)g1;
    }

    // ---- chain split: fwd consumes rows 1..tm, bwd rows slen+1..tm+1 -----
    const int fwd_mid = nmid >> 1;           // fwd middle steps (after init)
    const int bwd_mid = nmid - fwd_mid;      // = fwd_mid or fwd_mid+1
    const int common  = fwd_mid;

    // ---- preload obs: fwd rows 1..4; bwd W rows slen-2-u; bwd init row ---
    float cur_f[4], cur_b[4];
#pragma unroll
    for (int u = 0; u < 4; ++u) {
        const int rf = (u + 1 < T) ? (u + 1) : (T - 1);
        cur_f[u] = mine ? prow[(size_t)rf * L + lane] : 0.f;
        int rb = slen - 2 - u; rb = (rb > 0) ? rb : 0;
        cur_b[u] = mine ? prow[(size_t)rb * L + lane] : 0.f;
    }
    const float pv_b0 = mine ? prow[(size_t)(slen - 1) * L + lane] : 0.f;

    // ---- fwd init (row 1): qf = exp2(pred0)*psum; uniform SMALL -> c_base
    int Ci_f = 0, Ci_b = 0;
    const float c_base = SMALLF * LOG2E_F;
    float hf, hb;
    {
        const float q0 = psum * EXP2F((mine ? prow[lane] : 0.f) * LOG2E_F);
        const float sc = step_scale(q0, Ci_f);
        hf = q0 * sc;
    }
    // ---- bwd init (row slen+1 analytic): qb = E[:,63]; fold W of row slen
    {
        const float Elast = EXP2F(trans[lane * 64u + 63u] * LOG2E_F); // 0 on 62/63
        const float Wb0 = (bwd_mid > 0) ? (mine ? EXP2F(pv_b0 * LOG2E_F) : 0.f)
                                        : 1.0f;
        hb = Elast * Wb0;        // in [~2^-15, 2^15]: f16-safe unrenormed
    }

    // ---- paired middle steps, chunks of 4 --------------------------------
    for (int m0 = 0; m0 < common; m0 += 4) {
        float Wf[4], Wbn[4], nf[4], nb[4];
#pragma unroll
        for (int u = 0; u < 4; ++u) {
            Wf[u]  = EXP2F(cur_f[u] * LOG2E_F);                  // 1 on 62/63
            Wbn[u] = mine ? EXP2F(cur_b[u] * LOG2E_F) : 0.f;     // 0 on 62/63
        }
#pragma unroll
        for (int u = 0; u < 4; ++u) {            // prefetch next chunk
            int rf = m0 + 5 + u; rf = (rf < T) ? rf : (T - 1);
            nf[u] = mine ? prow[(size_t)rf * L + lane] : 0.f;
            int rb = slen - 6 - m0 - u; rb = (rb > 0) ? rb : 0;
            nb[u] = mine ? prow[(size_t)rb * L + lane] : 0.f;
        }
#pragma unroll
        for (int u = 0; u < 4; ++u) {
            if (m0 + u < common) {               // wave-uniform predicate
                const float ssf = step_ss(hf, Eh_f, b2);   // independent
                const float ssb = step_ss(hb, Eh_b, b2);   // chains: overlap
                const float scf = step_scale(ssf, Ci_f);
                const float scb = step_scale(ssb, Ci_b);
                hf = ssf * (Wf[u] * scf);
                const float wN = (m0 + u + 1 < bwd_mid) ? Wbn[u] : 1.0f;
                hb = ssb * (wN * scb);
            }
        }
#pragma unroll
        for (int u = 0; u < 4; ++u) { cur_f[u] = nf[u]; cur_b[u] = nb[u]; }
    }

    // ---- one extra bwd step when nmid is odd (last step: W = 1) ----------
    if (bwd_mid > common) {
        const float ssb = step_ss(hb, Eh_b, b2);
        const float scb = step_scale(ssb, Ci_b);
        hb = ssb * scb;
    }

    // ---- combine at tm: S = sum_i qf_i * qb_i (hb = 0 on lanes 62/63) ----
    {
        float p = hf * hb;
#pragma unroll
        for (int k = 32; k >= 1; k >>= 1)
            p += __shfl_xor(p, k, 64);
#pragma unroll
        for (int k = 32; k >= 1; k >>= 1)
            gacc += __shfl_xor(gacc, k, 64);

        if (lane == 0) {
            const float logZ2 = c_base + (float)(Ci_f + Ci_b) + LOG2F(p);
            atomicAdd(out, LN2_F * logZ2 - gacc);
        }
    }
}

extern "C" void kernel_launch(void* const* d_in, const int* in_sizes, int n_in,
                              void* d_out, int out_size, void* d_ws, size_t ws_size,
                              hipStream_t stream) {
    const float* pred  = (const float*)d_in[0];
    const int*   ref   = (const int*)  d_in[1];
    const int*   slen  = (const int*)  d_in[2];
    const float* trans = (const float*)d_in[3];

    const int B = in_sizes[2];                 // 1024
    const int T = in_sizes[1] / B;             // 512
    const int L = in_sizes[0] / in_sizes[1];   // 62

    hipMemsetAsync(d_out, 0, sizeof(float), stream);
    crf_fused_kernel<<<B, 64, 0, stream>>>(pred, ref, slen, trans,
                                           (float*)d_out, T, L);
}